// Round 12
// baseline (1931.204 us; speedup 1.0000x reference)
//
#include <hip/hip_runtime.h>

#define D_FEAT 256
constexpr int N_CHEM = 200000;
constexpr int N_DIS  = 200000;
constexpr int N_EDGE = 500000;
constexpr int NROWS  = 200000;
constexpr int NPAD   = 200064;   // 128 * 1563
constexpr int NCNT   = 4 * NROWS;      // 800000 concatenated counts
constexpr int NEALL  = 4 * N_EDGE;     // 2000000 concatenated edges

// prep_k grid partition
constexpr int PB_CNT = (NEALL + 255) / 256;          // 7813 count blocks
constexpr int PB_CVT = NROWS * D_FEAT / 4 / 256;     // 50000 cvt blocks per array
constexpr int PB_WT  = 1538;                         // wt blocks per layer

typedef _Float16 f16x8 __attribute__((ext_vector_type(8)));
typedef _Float16 f16x4 __attribute__((ext_vector_type(4)));
typedef float    f32x4 __attribute__((ext_vector_type(4)));

__device__ __forceinline__ void gload_lds16(const void* g, void* l) {
    __builtin_amdgcn_global_load_lds(
        (const __attribute__((address_space(1))) void*)g,
        (__attribute__((address_space(3))) void*)l, 16, 0, 0);
}

// ---------------------------------------------------------------------------
// Fused prep: edge counting + fp32->fp16 conversion + weight transpose.
__global__ __launch_bounds__(256) void prep_k(
    const int* __restrict__ e0, const int* __restrict__ e1,
    const int* __restrict__ e2, const int* __restrict__ e3,
    int* __restrict__ cnt,
    const float* __restrict__ x_chem, _Float16* __restrict__ xb_chem,
    const float* __restrict__ x_dis,  _Float16* __restrict__ xb_dis,
    const float* __restrict__ Wl, const float* __restrict__ Wr,
    const float* __restrict__ bl,
    _Float16* __restrict__ WT_dis, _Float16* __restrict__ WT_chem,
    float* __restrict__ bsum) {
    const int b = blockIdx.x;
    if (b < PB_CNT) {
        const int g = b * 256 + threadIdx.x;
        if (g >= NEALL) return;
        const int r = g / N_EDGE;
        const int le = g - r * N_EDGE;
        const int* e = (r == 0) ? e0 : (r == 1) ? e1 : (r == 2) ? e2 : e3;
        atomicAdd(&cnt[r * NROWS + e[N_EDGE + le]], 1);
    } else if (b < PB_CNT + 2 * PB_CVT) {
        const int b1 = b - PB_CNT;
        const float* in = (b1 < PB_CVT) ? x_chem : x_dis;
        _Float16* out = (b1 < PB_CVT) ? xb_chem : xb_dis;
        const int i = (b1 % PB_CVT) * 256 + threadIdx.x;
        const float4 v = reinterpret_cast<const float4*>(in)[i];
        f16x4 o;
        o[0] = (_Float16)v.x; o[1] = (_Float16)v.y;
        o[2] = (_Float16)v.z; o[3] = (_Float16)v.w;
        reinterpret_cast<f16x4*>(out)[i] = o;
    } else {
        const int b2 = b - PB_CNT - 2 * PB_CVT;
        const int l = b2 / PB_WT;
        const int idx = (b2 % PB_WT) * 256 + threadIdx.x;
        const float* Wl_l = Wl + (size_t)l * 4 * 65536;
        const float* Wr_l = Wr + (size_t)l * 4 * 65536;
        if (idx < 262144) {
            const int n = idx >> 10, k = idx & 1023, seg = k >> 8, kk = k & 255;
            float v;
            if (seg == 0)
                v = Wr_l[kk * 256 + n] + Wr_l[65536 + kk * 256 + n] + Wr_l[3 * 65536 + kk * 256 + n];
            else if (seg == 1) v = Wl_l[kk * 256 + n];
            else if (seg == 2) v = Wl_l[65536 + kk * 256 + n];
            else               v = Wl_l[3 * 65536 + kk * 256 + n];
            WT_dis[(size_t)l * 262144 + idx] = (_Float16)v;
        } else if (idx < 393216) {
            const int li = idx - 262144;
            const int n = li >> 9, k = li & 511, seg = k >> 8, kk = k & 255;
            const float v = (seg == 0) ? Wr_l[2 * 65536 + kk * 256 + n]
                                       : Wl_l[2 * 65536 + kk * 256 + n];
            WT_chem[(size_t)l * 131072 + li] = (_Float16)v;
        } else if (idx < 393216 + 256) {
            const int n = idx - 393216;
            const float* bb = bl + (size_t)l * 1024;
            bsum[l * 256 + n] = bb[n] + bb[256 + n] + bb[3 * 256 + n];
        }
    }
}

// ---------------------------------------------------------------------------
// scan phase 1: per-256-block exclusive scan; writes local offs AND cursor.
__global__ __launch_bounds__(256) void scan1_k(const int* __restrict__ cnt,
                                               int* __restrict__ offs,
                                               int* __restrict__ cursor,
                                               int* __restrict__ bsums, int n) {
    __shared__ int s[256];
    const int t = threadIdx.x;
    const int i = blockIdx.x * 256 + t;
    const int v = (i < n) ? cnt[i] : 0;
    s[t] = v;
    __syncthreads();
#pragma unroll
    for (int d = 1; d < 256; d <<= 1) {
        const int x = (t >= d) ? s[t - d] : 0;
        __syncthreads();
        s[t] += x;
        __syncthreads();
    }
    if (i < n) {
        const int o = s[t] - v;
        offs[i] = o;
        cursor[i] = o;
    }
    if (t == 255) bsums[blockIdx.x] = s[255];
}

// scan phase 2: single block, 4 elems/thread, in-place exclusive (nb<=4096)
__global__ __launch_bounds__(1024) void scan2_k(int* __restrict__ bsums, int nb) {
    __shared__ int s[1024];
    const int t = threadIdx.x;
    int v[4];
    int sum = 0;
#pragma unroll
    for (int q = 0; q < 4; ++q) {
        const int i = t * 4 + q;
        v[q] = (i < nb) ? bsums[i] : 0;
        sum += v[q];
    }
    s[t] = sum;
    __syncthreads();
#pragma unroll
    for (int d = 1; d < 1024; d <<= 1) {
        const int x = (t >= d) ? s[t - d] : 0;
        __syncthreads();
        s[t] += x;
        __syncthreads();
    }
    int base = s[t] - sum;
#pragma unroll
    for (int q = 0; q < 4; ++q) {
        const int i = t * 4 + q;
        if (i < nb) {
            const int tmp = v[q];
            bsums[i] = base;
            base += tmp;
        }
    }
}

// CSR fill: global position = local cursor bump + bsums block offset
__global__ __launch_bounds__(256) void fill_all_k(
    const int* __restrict__ e0, const int* __restrict__ e1,
    const int* __restrict__ e2, const int* __restrict__ e3,
    int* __restrict__ cursor, const int* __restrict__ bsums,
    int* __restrict__ csr) {
    const int g = blockIdx.x * 256 + threadIdx.x;
    if (g >= NEALL) return;
    const int r = g / N_EDGE;
    const int le = g - r * N_EDGE;
    const int* e = (r == 0) ? e0 : (r == 1) ? e1 : (r == 2) ? e2 : e3;
    const int d = r * NROWS + e[N_EDGE + le];
    const int p = atomicAdd(&cursor[d], 1) + bsums[d >> 8];
    csr[p] = e[le];
}

// ---------------------------------------------------------------------------
// gather-mean body (identical to round-10/11, passing): 4 rows per wave,
// x4-unrolled predicated edge loop, fp32 accum, fp16 in/out, no atomics.
__device__ __forceinline__ void gather_body(
    const _Float16* __restrict__ srcA, const _Float16* __restrict__ srcB,
    const int* __restrict__ csr, const int* __restrict__ offs,
    const int* __restrict__ bsums, const int* __restrict__ cnt,
    _Float16* __restrict__ gbuf, int crp, int base, int rows, int gx, int gy) {
    const int rel = (gy == 0) ? 0 : (gy == 1) ? 1 : (gy == 2) ? 3 : 2;
    const _Float16* x = (gy < 2) ? srcA : srcB;
    _Float16* agg = gbuf + (size_t)gy * crp * D_FEAT;

    const int wid = threadIdx.x >> 6;
    const int lane = threadIdx.x & 63;
    const int grp = lane >> 4;
    const int li  = lane & 15;
    const int lrow = gx * 16 + wid * 4 + grp;
    if (lrow >= rows) return;
    const int g = rel * NROWS + base + lrow;
    const int start = offs[g] + bsums[g >> 8];
    const int n = cnt[g];
    float a0[8] = {0,0,0,0,0,0,0,0}, a1[8] = {0,0,0,0,0,0,0,0};
    const _Float16* xb = x + li * 16;
    for (int j = 0; j < n; j += 4) {
        const int rem = n - j;
        const int i0 = start + j;
        const int c1 = (rem > 1) ? 1 : 0;
        const int c2 = (rem > 2) ? 2 : 0;
        const int c3 = (rem > 3) ? 3 : 0;
        const int s0 = csr[i0];
        const int s1 = csr[i0 + c1];
        const int s2 = csr[i0 + c2];
        const int s3 = csr[i0 + c3];
        const float w1 = c1 ? 1.f : 0.f;
        const float w2 = c2 ? 1.f : 0.f;
        const float w3 = c3 ? 1.f : 0.f;
        const f16x8 u0a = *reinterpret_cast<const f16x8*>(xb + (size_t)s0 * D_FEAT);
        const f16x8 u0b = *reinterpret_cast<const f16x8*>(xb + (size_t)s0 * D_FEAT + 8);
        const f16x8 u1a = *reinterpret_cast<const f16x8*>(xb + (size_t)s1 * D_FEAT);
        const f16x8 u1b = *reinterpret_cast<const f16x8*>(xb + (size_t)s1 * D_FEAT + 8);
        const f16x8 u2a = *reinterpret_cast<const f16x8*>(xb + (size_t)s2 * D_FEAT);
        const f16x8 u2b = *reinterpret_cast<const f16x8*>(xb + (size_t)s2 * D_FEAT + 8);
        const f16x8 u3a = *reinterpret_cast<const f16x8*>(xb + (size_t)s3 * D_FEAT);
        const f16x8 u3b = *reinterpret_cast<const f16x8*>(xb + (size_t)s3 * D_FEAT + 8);
#pragma unroll
        for (int q = 0; q < 8; ++q) {
            a0[q] += (float)u0a[q];
            a0[q] = fmaf(w1, (float)u1a[q], a0[q]);
            a0[q] = fmaf(w2, (float)u2a[q], a0[q]);
            a0[q] = fmaf(w3, (float)u3a[q], a0[q]);
            a1[q] += (float)u0b[q];
            a1[q] = fmaf(w1, (float)u1b[q], a1[q]);
            a1[q] = fmaf(w2, (float)u2b[q], a1[q]);
            a1[q] = fmaf(w3, (float)u3b[q], a1[q]);
        }
    }
    const float inv = 1.0f / fmaxf((float)n, 1.0f);
    f16x8 o0, o1;
#pragma unroll
    for (int q = 0; q < 8; ++q) {
        o0[q] = (_Float16)(a0[q] * inv);
        o1[q] = (_Float16)(a1[q] * inv);
    }
    _Float16* ap = agg + (size_t)lrow * D_FEAT + li * 16;
    *reinterpret_cast<f16x8*>(ap) = o0;
    *reinterpret_cast<f16x8*>(ap + 8) = o1;
}

// standalone gather (layer-start chunk 0)
__global__ __launch_bounds__(256) void gather_all_k(
    const _Float16* __restrict__ srcA, const _Float16* __restrict__ srcB,
    const int* __restrict__ csr, const int* __restrict__ offs,
    const int* __restrict__ bsums, const int* __restrict__ cnt,
    _Float16* __restrict__ gbuf, int crp, int base, int rows) {
    gather_body(srcA, srcB, csr, offs, bsums, cnt, gbuf, crp, base, rows,
                blockIdx.x, blockIdx.y);
}

// ---------------------------------------------------------------------------
// MFMA GEMM body. DBUF=true: 2-phase double-buffered (64 KB LDS, verified
// r7-r10). DBUF=false: single-buffered (32 KB LDS) — used inside fused_k so
// gather blocks keep high occupancy; its staging stalls are covered by
// co-resident gather waves (m114 overlap).
template <int NSEG, bool RELU_OUT, bool DBUF>
__device__ __forceinline__ void gemm_body(
    _Float16* __restrict__ AslBase, _Float16* __restrict__ BslBase,
    const _Float16* __restrict__ A0, const _Float16* __restrict__ A1,
    const _Float16* __restrict__ A2, const _Float16* __restrict__ A3,
    const _Float16* __restrict__ WT, const float* __restrict__ bias,
    float* __restrict__ Cf, _Float16* __restrict__ Ch, int vrows,
    int row0, int col0) {
    constexpr int KT = NSEG * 256;
    constexpr int NS = KT / 64;
    const int t = threadIdx.x;
    const int w = t >> 6, l = t & 63;
    const int wm = w & 1, wn = w >> 1;
    const int fr = l & 15, ko = (l >> 4) << 3;

    f32x4 acc[4][4];
#pragma unroll
    for (int m = 0; m < 4; ++m)
#pragma unroll
        for (int n = 0; n < 4; ++n) acc[m][n] = f32x4{0.f, 0.f, 0.f, 0.f};

    const int srow = t >> 3;
    const int schk = t & 7;
    const int gchk = schk ^ (srow & 7);
    const int rsw  = (fr & 7) << 3;

    auto STAGE = [&](int buf, int ks) {
        const int seg = ks >> 2;
        const _Float16* Ab = (seg == 0) ? A0 : ((seg == 1) ? A1 : ((seg == 2) ? A2 : A3));
        const int kofs = ((ks & 3) << 6) + gchk * 8;
        _Float16* asl = AslBase + buf * 8192;
        _Float16* bsl = BslBase + buf * 8192;
#pragma unroll
        for (int is = 0; is < 4; ++is) {
            gload_lds16(Ab + (size_t)(row0 + is * 32 + srow) * D_FEAT + kofs,
                        asl + is * 2048 + w * 512);
            gload_lds16(WT + (size_t)(col0 + is * 32 + srow) * KT + seg * 256 + kofs,
                        bsl + is * 2048 + w * 512);
        }
    };

    auto COMPUTE = [&](int buf) {
        const _Float16* asl = AslBase + buf * 8192;
        const _Float16* bsl = BslBase + buf * 8192;
#pragma unroll
        for (int kk = 0; kk < 64; kk += 32) {
            f16x8 af[4], bf[4];
            const int ksw = (kk + ko) ^ rsw;
#pragma unroll
            for (int m = 0; m < 4; ++m)
                af[m] = *reinterpret_cast<const f16x8*>(&asl[(wm * 64 + m * 16 + fr) * 64 + ksw]);
#pragma unroll
            for (int n = 0; n < 4; ++n)
                bf[n] = *reinterpret_cast<const f16x8*>(&bsl[(wn * 64 + n * 16 + fr) * 64 + ksw]);
#pragma unroll
            for (int m = 0; m < 4; ++m)
#pragma unroll
                for (int n = 0; n < 4; ++n)
                    acc[m][n] = __builtin_amdgcn_mfma_f32_16x16x32_f16(af[m], bf[n], acc[m][n], 0, 0, 0);
        }
    };

    if constexpr (DBUF) {
        STAGE(0, 0);
        int cur = 0;
        for (int ks = 0; ks < NS - 1; ++ks) {
            STAGE(cur ^ 1, ks + 1);
            asm volatile("s_waitcnt vmcnt(8)" ::: "memory");
            __builtin_amdgcn_s_barrier();
            __builtin_amdgcn_sched_barrier(0);
            COMPUTE(cur);
            __builtin_amdgcn_sched_barrier(0);
            __builtin_amdgcn_s_barrier();
            __builtin_amdgcn_sched_barrier(0);
            cur ^= 1;
        }
        asm volatile("s_waitcnt vmcnt(0)" ::: "memory");
        __builtin_amdgcn_s_barrier();
        __builtin_amdgcn_sched_barrier(0);
        COMPUTE(cur);
    } else {
        for (int ks = 0; ks < NS; ++ks) {
            STAGE(0, ks);
            __syncthreads();                 // vmcnt(0)+lgkmcnt(0)+barrier
            COMPUTE(0);
            __syncthreads();                 // reads done before next STAGE
        }
    }

    const int cro = (l >> 4) << 2;
#pragma unroll
    for (int n = 0; n < 4; ++n) {
        const int col = col0 + wn * 64 + n * 16 + fr;
        const float bi = bias[col];
#pragma unroll
        for (int m = 0; m < 4; ++m) {
            const int rbase = row0 + wm * 64 + m * 16 + cro;
#pragma unroll
            for (int j = 0; j < 4; ++j) {
                const int r = rbase + j;
                if (r < vrows) {
                    const float v = acc[m][n][j] + bi;
                    if constexpr (RELU_OUT)
                        Ch[(size_t)r * D_FEAT + col] = (_Float16)fmaxf(v, 0.f);
                    else
                        Cf[(size_t)r * D_FEAT + col] = v;
                }
            }
        }
    }
}

// standalone fused dis+chem GEMM (layer-end chunk): 2-phase, 64 KB LDS
template <bool RELU_OUT>
__global__ __launch_bounds__(256) void gemm2_k(
    const _Float16* __restrict__ A0d, const _Float16* __restrict__ A1,
    const _Float16* __restrict__ A2, const _Float16* __restrict__ A3,
    const _Float16* __restrict__ WTd, const float* __restrict__ biasd,
    float* __restrict__ Cfd, _Float16* __restrict__ Chd,
    const _Float16* __restrict__ A0c, const _Float16* __restrict__ A4,
    const _Float16* __restrict__ WTc, const float* __restrict__ biasc,
    float* __restrict__ Cfc, _Float16* __restrict__ Chc, int vrows) {
    __shared__ _Float16 Asl[2 * 128 * 64];
    __shared__ _Float16 Bsl[2 * 128 * 64];
    const int row0 = blockIdx.x * 128, col0 = blockIdx.y * 128;
    if (blockIdx.z == 0)
        gemm_body<4, RELU_OUT, true>(Asl, Bsl, A0d, A1, A2, A3, WTd, biasd, Cfd, Chd, vrows, row0, col0);
    else
        gemm_body<2, RELU_OUT, true>(Asl, Bsl, A0c, A4, nullptr, nullptr, WTc, biasc, Cfc, Chc, vrows, row0, col0);
}

// ---------------------------------------------------------------------------
// Pipelined dispatch: gemm(chunk i, single-buffer 32 KB) + gather(chunk i+1)
// in ONE kernel, stride-9 interleave. 32 KB LDS keeps ALL blocks at 4-5/CU
// (r11's 64 KB starved the gather blocks); gather waves cover the
// single-buffer gemm's staging stalls.
template <bool RELU_OUT>
__global__ __launch_bounds__(256) void fused_k(
    // gemm chunk i
    const _Float16* __restrict__ A0d, const _Float16* __restrict__ A1,
    const _Float16* __restrict__ A2, const _Float16* __restrict__ A3,
    const _Float16* __restrict__ WTd, const float* __restrict__ biasd,
    float* __restrict__ Cfd, _Float16* __restrict__ Chd,
    const _Float16* __restrict__ A0c, const _Float16* __restrict__ A4,
    const _Float16* __restrict__ WTc, const float* __restrict__ biasc,
    float* __restrict__ Cfc, _Float16* __restrict__ Chc,
    int vrows, int gemmBX, int G,
    // gather chunk i+1
    const _Float16* __restrict__ srcA, const _Float16* __restrict__ srcB,
    const int* __restrict__ csr, const int* __restrict__ offs,
    const int* __restrict__ bsums, const int* __restrict__ cnt,
    _Float16* __restrict__ gbuf, int crp, int gbase, int grows,
    int gxExt, int H) {
    __shared__ _Float16 Asl[128 * 64];
    __shared__ _Float16 Bsl[128 * 64];
    const int b = blockIdx.x;
    if ((b % 9) == 0 && (b / 9) < G) {
        const int gi = b / 9;
        const int x = gi % gemmBX;
        const int yz = gi / gemmBX;
        const int row0 = x * 128, col0 = (yz & 1) * 128;
        if ((yz >> 1) == 0)
            gemm_body<4, RELU_OUT, false>(Asl, Bsl, A0d, A1, A2, A3, WTd, biasd, Cfd, Chd, vrows, row0, col0);
        else
            gemm_body<2, RELU_OUT, false>(Asl, Bsl, A0c, A4, nullptr, nullptr, WTc, biasc, Cfc, Chc, vrows, row0, col0);
    } else {
        int ng = (b + 8) / 9;
        if (ng > G) ng = G;
        const int gi = b - ng;
        if (gi >= H) return;
        gather_body(srcA, srcB, csr, offs, bsums, cnt, gbuf, crp, gbase, grows,
                    gi % gxExt, gi / gxExt);
    }
}

// ---------------------------------------------------------------------------
extern "C" void kernel_launch(void* const* d_in, const int* in_sizes, int n_in,
                              void* d_out, int out_size, void* d_ws, size_t ws_size,
                              hipStream_t stream) {
    const float* x_chem = (const float*)d_in[0];
    const float* x_dis  = (const float*)d_in[1];
    const float* Wl     = (const float*)d_in[2];
    const float* bl     = (const float*)d_in[3];
    const float* Wr     = (const float*)d_in[4];
    const int* ei[4] = {(const int*)d_in[5],   // cause  (chem->dis)
                        (const int*)d_in[6],   // relate (chem->dis)
                        (const int*)d_in[7],   // rev    (dis->chem)
                        (const int*)d_in[8]};  // child  (dis->dis)

    float* out_chem = (float*)d_out;
    float* out_dis  = out_chem + (size_t)N_CHEM * D_FEAT;

    // ---- workspace carve (bytes); padded feature buffers = NPAD rows ----
    constexpr size_t FB = (size_t)NPAD * D_FEAT * 2;   // 102,432,768
    char* w = (char*)d_ws;
    _Float16* h_chem  = (_Float16*)(w);
    _Float16* h_dis   = (_Float16*)(w + FB);
    _Float16* xb_chem = (_Float16*)(w + 2 * FB);
    _Float16* xb_dis  = (_Float16*)(w + 3 * FB);
    char* p = w + 4 * FB;
    int* csr    = (int*)(p);              p += 8000000;
    int* counts = (int*)(p);              p += 3200000;
    int* offs   = (int*)(p);              p += 3200000;
    int* cursor = (int*)(p);              p += 3200000;
    int* bsums  = (int*)(p);              p += 16384;
    _Float16* WT_dis  = (_Float16*)(p);   p += 1048576;
    _Float16* WT_chem = (_Float16*)(p);   p += 524288;
    float* bsum = (float*)(p);            p += 2048;
    _Float16* chunkbuf = (_Float16*)(p);  // 8 * crp * 512 bytes (double-buffered)

    // chunk rows: 8 agg slots (2 buffer sets x 4 relations)
    const size_t FIXED = (size_t)(p - w);
    long long avail = (long long)ws_size - (long long)FIXED;
    int crp = 51200;
    if (avail < (long long)crp * 4096) {
        long long c = avail / 4096;
        if (c > NPAD) c = NPAD;
        crp = (int)(c & ~127LL);
        if (crp < 128) crp = 128;
    }
    const int nc = (NROWS + crp - 1) / crp;
    const size_t setStride = (size_t)4 * crp * D_FEAT;

    // ---- CSR build + prep: 5 dispatches ----
    const int eall_grid = (NEALL + 255) / 256;
    const int scan_blocks = (NCNT + 255) / 256;         // 3125
    hipMemsetAsync(counts, 0, NCNT * sizeof(int), stream);
    prep_k<<<PB_CNT + 2 * PB_CVT + 2 * PB_WT, 256, 0, stream>>>(
        ei[0], ei[1], ei[2], ei[3], counts,
        x_chem, xb_chem, x_dis, xb_dis, Wl, Wr, bl, WT_dis, WT_chem, bsum);
    scan1_k<<<scan_blocks, 256, 0, stream>>>(counts, offs, cursor, bsums, NCNT);
    scan2_k<<<1, 1024, 0, stream>>>(bsums, scan_blocks);
    fill_all_k<<<eall_grid, 256, 0, stream>>>(ei[0], ei[1], ei[2], ei[3], cursor, bsums, csr);

    // ---- two layers, software-pipelined chunks ----
    for (int layer = 0; layer < 2; ++layer) {
        const _Float16* srcA = layer ? h_chem : xb_chem;   // chem-sourced relations
        const _Float16* srcB = layer ? h_dis  : xb_dis;    // dis-sourced relations
        const _Float16* WTd = WT_dis + (size_t)layer * 262144;
        const _Float16* WTc = WT_chem + (size_t)layer * 131072;
        const float* biasd = bsum + layer * 256;
        const float* biasc = bl + (layer * 4 + 2) * 256;

        auto launch_gemm_ptrs = [&](int i, const _Float16*& A0d, const _Float16*& A0c,
                                    float*& Cfd, _Float16*& Chd, float*& Cfc,
                                    _Float16*& Chc, _Float16*& set) {
            const size_t boff = (size_t)i * crp * D_FEAT;
            A0d = srcB + boff;                 // dis root = dis features
            A0c = srcA + boff;                 // chem root = chem features
            set = chunkbuf + (size_t)(i & 1) * setStride;
            if (layer == 0) {
                Cfd = nullptr; Chd = h_dis + boff;
                Cfc = nullptr; Chc = h_chem + boff;
            } else {
                Cfd = out_dis + boff;  Chd = nullptr;
                Cfc = out_chem + boff; Chc = nullptr;
            }
        };

        // gather chunk 0 into set 0
        {
            const int rows0 = (NROWS < crp) ? NROWS : crp;
            gather_all_k<<<dim3((rows0 + 15) / 16, 4), 256, 0, stream>>>(
                srcA, srcB, csr, offs, bsums, counts, chunkbuf, crp, 0, rows0);
        }
        // fused: gemm(i) + gather(i+1)
        for (int i = 0; i + 1 < nc; ++i) {
            const int base_i = i * crp;
            const int rows_i = (NROWS - base_i < crp) ? (NROWS - base_i) : crp;
            const int base_n = (i + 1) * crp;
            const int rows_n = (NROWS - base_n < crp) ? (NROWS - base_n) : crp;
            const int BX = ((rows_i + 127) & ~127) / 128;
            const int G = BX * 4;
            const int gxExt = (rows_n + 15) / 16;
            const int H = gxExt * 4;
            int T = 9 * G - 8;
            if (G + H > T) T = G + H;
            const _Float16 *A0d, *A0c; float *Cfd, *Cfc; _Float16 *Chd, *Chc, *set;
            launch_gemm_ptrs(i, A0d, A0c, Cfd, Chd, Cfc, Chc, set);
            _Float16* gset = chunkbuf + (size_t)((i + 1) & 1) * setStride;
            if (layer == 0)
                fused_k<true><<<T, 256, 0, stream>>>(
                    A0d, set, set + crp * D_FEAT, set + 2 * (size_t)crp * D_FEAT,
                    WTd, biasd, Cfd, Chd,
                    A0c, set + 3 * (size_t)crp * D_FEAT, WTc, biasc, Cfc, Chc,
                    rows_i, BX, G,
                    srcA, srcB, csr, offs, bsums, counts, gset, crp, base_n, rows_n,
                    gxExt, H);
            else
                fused_k<false><<<T, 256, 0, stream>>>(
                    A0d, set, set + crp * D_FEAT, set + 2 * (size_t)crp * D_FEAT,
                    WTd, biasd, Cfd, Chd,
                    A0c, set + 3 * (size_t)crp * D_FEAT, WTc, biasc, Cfc, Chc,
                    rows_i, BX, G,
                    srcA, srcB, csr, offs, bsums, counts, gset, crp, base_n, rows_n,
                    gxExt, H);
        }
        // final chunk gemm (no next gather): 2-phase standalone
        {
            const int i = nc - 1;
            const int base_i = i * crp;
            const int rows_i = NROWS - base_i;
            const int BX = ((rows_i + 127) & ~127) / 128;
            const _Float16 *A0d, *A0c; float *Cfd, *Cfc; _Float16 *Chd, *Chc, *set;
            launch_gemm_ptrs(i, A0d, A0c, Cfd, Chd, Cfc, Chc, set);
            if (layer == 0)
                gemm2_k<true><<<dim3(BX, 2, 2), 256, 0, stream>>>(
                    A0d, set, set + crp * D_FEAT, set + 2 * (size_t)crp * D_FEAT,
                    WTd, biasd, Cfd, Chd,
                    A0c, set + 3 * (size_t)crp * D_FEAT, WTc, biasc, Cfc, Chc, rows_i);
            else
                gemm2_k<false><<<dim3(BX, 2, 2), 256, 0, stream>>>(
                    A0d, set, set + crp * D_FEAT, set + 2 * (size_t)crp * D_FEAT,
                    WTd, biasd, Cfd, Chd,
                    A0c, set + 3 * (size_t)crp * D_FEAT, WTc, biasc, Cfc, Chc, rows_i);
        }
    }
}

// Round 13
// 1658.691 us; speedup vs baseline: 1.1643x; 1.1643x over previous
//
#include <hip/hip_runtime.h>

#define D_FEAT 256
constexpr int N_CHEM = 200000;
constexpr int N_DIS  = 200000;
constexpr int N_EDGE = 500000;
constexpr int NROWS  = 200000;
constexpr int NPAD   = 200064;   // 128 * 1563
constexpr int NCNT   = 4 * NROWS;      // 800000 concatenated counts
constexpr int NEALL  = 4 * N_EDGE;     // 2000000 concatenated edges

// prep_k grid partition
constexpr int PB_CNT = (NEALL + 255) / 256;          // 7813 count blocks
constexpr int PB_CVT = NROWS * D_FEAT / 4 / 256;     // 50000 cvt blocks per array
constexpr int PB_WT  = 1538;                         // wt blocks per layer

typedef _Float16 f16x8 __attribute__((ext_vector_type(8)));
typedef _Float16 f16x4 __attribute__((ext_vector_type(4)));
typedef float    f32x4 __attribute__((ext_vector_type(4)));

__device__ __forceinline__ void gload_lds16(const void* g, void* l) {
    __builtin_amdgcn_global_load_lds(
        (const __attribute__((address_space(1))) void*)g,
        (__attribute__((address_space(3))) void*)l, 16, 0, 0);
}

// ---------------------------------------------------------------------------
// Fused prep: edge counting + fp32->fp16 conversion + weight transpose.
// (identical to round-10 passing version)
__global__ __launch_bounds__(256) void prep_k(
    const int* __restrict__ e0, const int* __restrict__ e1,
    const int* __restrict__ e2, const int* __restrict__ e3,
    int* __restrict__ cnt,
    const float* __restrict__ x_chem, _Float16* __restrict__ xb_chem,
    const float* __restrict__ x_dis,  _Float16* __restrict__ xb_dis,
    const float* __restrict__ Wl, const float* __restrict__ Wr,
    const float* __restrict__ bl,
    _Float16* __restrict__ WT_dis, _Float16* __restrict__ WT_chem,
    float* __restrict__ bsum) {
    const int b = blockIdx.x;
    if (b < PB_CNT) {
        const int g = b * 256 + threadIdx.x;
        if (g >= NEALL) return;
        const int r = g / N_EDGE;
        const int le = g - r * N_EDGE;
        const int* e = (r == 0) ? e0 : (r == 1) ? e1 : (r == 2) ? e2 : e3;
        atomicAdd(&cnt[r * NROWS + e[N_EDGE + le]], 1);
    } else if (b < PB_CNT + 2 * PB_CVT) {
        const int b1 = b - PB_CNT;
        const float* in = (b1 < PB_CVT) ? x_chem : x_dis;
        _Float16* out = (b1 < PB_CVT) ? xb_chem : xb_dis;
        const int i = (b1 % PB_CVT) * 256 + threadIdx.x;
        const float4 v = reinterpret_cast<const float4*>(in)[i];
        f16x4 o;
        o[0] = (_Float16)v.x; o[1] = (_Float16)v.y;
        o[2] = (_Float16)v.z; o[3] = (_Float16)v.w;
        reinterpret_cast<f16x4*>(out)[i] = o;
    } else {
        const int b2 = b - PB_CNT - 2 * PB_CVT;
        const int l = b2 / PB_WT;
        const int idx = (b2 % PB_WT) * 256 + threadIdx.x;
        const float* Wl_l = Wl + (size_t)l * 4 * 65536;
        const float* Wr_l = Wr + (size_t)l * 4 * 65536;
        if (idx < 262144) {
            const int n = idx >> 10, k = idx & 1023, seg = k >> 8, kk = k & 255;
            float v;
            if (seg == 0)
                v = Wr_l[kk * 256 + n] + Wr_l[65536 + kk * 256 + n] + Wr_l[3 * 65536 + kk * 256 + n];
            else if (seg == 1) v = Wl_l[kk * 256 + n];
            else if (seg == 2) v = Wl_l[65536 + kk * 256 + n];
            else               v = Wl_l[3 * 65536 + kk * 256 + n];
            WT_dis[(size_t)l * 262144 + idx] = (_Float16)v;
        } else if (idx < 393216) {
            const int li = idx - 262144;
            const int n = li >> 9, k = li & 511, seg = k >> 8, kk = k & 255;
            const float v = (seg == 0) ? Wr_l[2 * 65536 + kk * 256 + n]
                                       : Wl_l[2 * 65536 + kk * 256 + n];
            WT_chem[(size_t)l * 131072 + li] = (_Float16)v;
        } else if (idx < 393216 + 256) {
            const int n = idx - 393216;
            const float* bb = bl + (size_t)l * 1024;
            bsum[l * 256 + n] = bb[n] + bb[256 + n] + bb[3 * 256 + n];
        }
    }
}

// ---------------------------------------------------------------------------
// scan phase 1: per-256-block exclusive scan; writes local offs AND cursor.
__global__ __launch_bounds__(256) void scan1_k(const int* __restrict__ cnt,
                                               int* __restrict__ offs,
                                               int* __restrict__ cursor,
                                               int* __restrict__ bsums, int n) {
    __shared__ int s[256];
    const int t = threadIdx.x;
    const int i = blockIdx.x * 256 + t;
    const int v = (i < n) ? cnt[i] : 0;
    s[t] = v;
    __syncthreads();
#pragma unroll
    for (int d = 1; d < 256; d <<= 1) {
        const int x = (t >= d) ? s[t - d] : 0;
        __syncthreads();
        s[t] += x;
        __syncthreads();
    }
    if (i < n) {
        const int o = s[t] - v;
        offs[i] = o;
        cursor[i] = o;
    }
    if (t == 255) bsums[blockIdx.x] = s[255];
}

// scan phase 2: single block, 4 elems/thread, in-place exclusive (nb<=4096)
__global__ __launch_bounds__(1024) void scan2_k(int* __restrict__ bsums, int nb) {
    __shared__ int s[1024];
    const int t = threadIdx.x;
    int v[4];
    int sum = 0;
#pragma unroll
    for (int q = 0; q < 4; ++q) {
        const int i = t * 4 + q;
        v[q] = (i < nb) ? bsums[i] : 0;
        sum += v[q];
    }
    s[t] = sum;
    __syncthreads();
#pragma unroll
    for (int d = 1; d < 1024; d <<= 1) {
        const int x = (t >= d) ? s[t - d] : 0;
        __syncthreads();
        s[t] += x;
        __syncthreads();
    }
    int base = s[t] - sum;
#pragma unroll
    for (int q = 0; q < 4; ++q) {
        const int i = t * 4 + q;
        if (i < nb) {
            const int tmp = v[q];
            bsums[i] = base;
            base += tmp;
        }
    }
}

// CSR fill: global position = local cursor bump + bsums block offset
__global__ __launch_bounds__(256) void fill_all_k(
    const int* __restrict__ e0, const int* __restrict__ e1,
    const int* __restrict__ e2, const int* __restrict__ e3,
    int* __restrict__ cursor, const int* __restrict__ bsums,
    int* __restrict__ csr) {
    const int g = blockIdx.x * 256 + threadIdx.x;
    if (g >= NEALL) return;
    const int r = g / N_EDGE;
    const int le = g - r * N_EDGE;
    const int* e = (r == 0) ? e0 : (r == 1) ? e1 : (r == 2) ? e2 : e3;
    const int d = r * NROWS + e[N_EDGE + le];
    const int p = atomicAdd(&cursor[d], 1) + bsums[d >> 8];
    csr[p] = e[le];
}

// ---------------------------------------------------------------------------
// Fused gather-mean (identical to round-10 passing version): grid.y selects
// relation/source/agg-slot; 4 rows/wave (16-lane groups), x4-unrolled
// predicated edge loop, fp32 accum, fp16 in/out, no atomics.
__global__ __launch_bounds__(256) void gather_all_k(
    const _Float16* __restrict__ srcA, const _Float16* __restrict__ srcB,
    const int* __restrict__ csr, const int* __restrict__ offs,
    const int* __restrict__ bsums, const int* __restrict__ cnt,
    _Float16* __restrict__ chunkbuf, int crp, int base, int rows) {
    const int y = blockIdx.y;
    const int rel = (y == 0) ? 0 : (y == 1) ? 1 : (y == 2) ? 3 : 2;
    const _Float16* x = (y < 2) ? srcA : srcB;
    _Float16* agg = chunkbuf + (size_t)y * crp * D_FEAT;

    const int wid = threadIdx.x >> 6;
    const int lane = threadIdx.x & 63;
    const int grp = lane >> 4;
    const int li  = lane & 15;
    const int lrow = blockIdx.x * 16 + wid * 4 + grp;
    if (lrow >= rows) return;
    const int g = rel * NROWS + base + lrow;
    const int start = offs[g] + bsums[g >> 8];
    const int n = cnt[g];
    float a0[8] = {0,0,0,0,0,0,0,0}, a1[8] = {0,0,0,0,0,0,0,0};
    const _Float16* xb = x + li * 16;
    for (int j = 0; j < n; j += 4) {
        const int rem = n - j;
        const int i0 = start + j;
        const int c1 = (rem > 1) ? 1 : 0;
        const int c2 = (rem > 2) ? 2 : 0;
        const int c3 = (rem > 3) ? 3 : 0;
        const int s0 = csr[i0];
        const int s1 = csr[i0 + c1];
        const int s2 = csr[i0 + c2];
        const int s3 = csr[i0 + c3];
        const float w1 = c1 ? 1.f : 0.f;
        const float w2 = c2 ? 1.f : 0.f;
        const float w3 = c3 ? 1.f : 0.f;
        const f16x8 u0a = *reinterpret_cast<const f16x8*>(xb + (size_t)s0 * D_FEAT);
        const f16x8 u0b = *reinterpret_cast<const f16x8*>(xb + (size_t)s0 * D_FEAT + 8);
        const f16x8 u1a = *reinterpret_cast<const f16x8*>(xb + (size_t)s1 * D_FEAT);
        const f16x8 u1b = *reinterpret_cast<const f16x8*>(xb + (size_t)s1 * D_FEAT + 8);
        const f16x8 u2a = *reinterpret_cast<const f16x8*>(xb + (size_t)s2 * D_FEAT);
        const f16x8 u2b = *reinterpret_cast<const f16x8*>(xb + (size_t)s2 * D_FEAT + 8);
        const f16x8 u3a = *reinterpret_cast<const f16x8*>(xb + (size_t)s3 * D_FEAT);
        const f16x8 u3b = *reinterpret_cast<const f16x8*>(xb + (size_t)s3 * D_FEAT + 8);
#pragma unroll
        for (int q = 0; q < 8; ++q) {
            a0[q] += (float)u0a[q];
            a0[q] = fmaf(w1, (float)u1a[q], a0[q]);
            a0[q] = fmaf(w2, (float)u2a[q], a0[q]);
            a0[q] = fmaf(w3, (float)u3a[q], a0[q]);
            a1[q] += (float)u0b[q];
            a1[q] = fmaf(w1, (float)u1b[q], a1[q]);
            a1[q] = fmaf(w2, (float)u2b[q], a1[q]);
            a1[q] = fmaf(w3, (float)u3b[q], a1[q]);
        }
    }
    const float inv = 1.0f / fmaxf((float)n, 1.0f);
    f16x8 o0, o1;
#pragma unroll
    for (int q = 0; q < 8; ++q) {
        o0[q] = (_Float16)(a0[q] * inv);
        o1[q] = (_Float16)(a1[q] * inv);
    }
    _Float16* ap = agg + (size_t)lrow * D_FEAT + li * 16;
    *reinterpret_cast<f16x8*>(ap) = o0;
    *reinterpret_cast<f16x8*>(ap + 8) = o1;
}

// ---------------------------------------------------------------------------
// 2-phase double-buffered MFMA GEMM body, BN=256 A-reuse variant.
// Block: 512 thr = 8 waves (2m x 4n of 64x64), tile 128 rows x 256 cols
// (full N). A is staged ONCE per block (halves A-side global traffic vs the
// r10 two-col-block layout). LDS: A 2x16KB + B 2x32KB = 96 KB -> 1 block/CU
// x 8 waves = same 8 waves/CU occupancy as r10. Same verified XOR swizzle
// (source octet ^= row&7 at stage; read col elem ^= (fr&7)<<3) and counted
// vmcnt pipeline (6 loads per STAGE: 2 A-passes + 4 B-passes -> vmcnt(6)).
template <int NSEG, bool RELU_OUT>
__device__ __forceinline__ void gemm_body(
    _Float16* __restrict__ Asl, _Float16* __restrict__ Bsl,
    const _Float16* __restrict__ A0, const _Float16* __restrict__ A1,
    const _Float16* __restrict__ A2, const _Float16* __restrict__ A3,
    const _Float16* __restrict__ WT, const float* __restrict__ bias,
    float* __restrict__ Cf, _Float16* __restrict__ Ch, int vrows, int row0) {
    constexpr int KT = NSEG * 256;
    constexpr int NS = KT / 64;
    const int t = threadIdx.x;
    const int w = t >> 6, l = t & 63;
    const int wm = w >> 2, wn = w & 3;          // 2m x 4n wave grid
    const int fr = l & 15, ko = (l >> 4) << 3;

    f32x4 acc[4][4];
#pragma unroll
    for (int m = 0; m < 4; ++m)
#pragma unroll
        for (int n = 0; n < 4; ++n) acc[m][n] = f32x4{0.f, 0.f, 0.f, 0.f};

    const int srow = t >> 3;                    // 0..63
    const int schk = t & 7;                     // LDS slot octet
    const int gchk = schk ^ (srow & 7);         // pre-swizzled source octet
    const int rsw  = (fr & 7) << 3;             // read-side XOR (elements)

    auto STAGE = [&](int buf, int ks) {
        const int seg = ks >> 2;
        const _Float16* Ab = (seg == 0) ? A0 : ((seg == 1) ? A1 : ((seg == 2) ? A2 : A3));
        const int kofs = ((ks & 3) << 6) + gchk * 8;
        _Float16* asl = Asl + buf * 8192;
        _Float16* bsl = Bsl + buf * 16384;
        // A: 128 rows, 2 passes of 64 rows
#pragma unroll
        for (int is = 0; is < 2; ++is)
            gload_lds16(Ab + (size_t)(row0 + is * 64 + srow) * D_FEAT + kofs,
                        asl + is * 4096 + w * 512);
        // B: 256 cols (rows of WT), 4 passes of 64
#pragma unroll
        for (int is = 0; is < 4; ++is)
            gload_lds16(WT + (size_t)(is * 64 + srow) * KT + seg * 256 + kofs,
                        bsl + is * 4096 + w * 512);
    };

    auto COMPUTE = [&](int buf) {
        const _Float16* asl = Asl + buf * 8192;
        const _Float16* bsl = Bsl + buf * 16384;
#pragma unroll
        for (int kk = 0; kk < 64; kk += 32) {
            f16x8 af[4], bf[4];
            const int ksw = (kk + ko) ^ rsw;
#pragma unroll
            for (int m = 0; m < 4; ++m)
                af[m] = *reinterpret_cast<const f16x8*>(&asl[(wm * 64 + m * 16 + fr) * 64 + ksw]);
#pragma unroll
            for (int n = 0; n < 4; ++n)
                bf[n] = *reinterpret_cast<const f16x8*>(&bsl[(wn * 64 + n * 16 + fr) * 64 + ksw]);
#pragma unroll
            for (int m = 0; m < 4; ++m)
#pragma unroll
                for (int n = 0; n < 4; ++n)
                    acc[m][n] = __builtin_amdgcn_mfma_f32_16x16x32_f16(af[m], bf[n], acc[m][n], 0, 0, 0);
        }
    };

    STAGE(0, 0);
    int cur = 0;
    for (int ks = 0; ks < NS - 1; ++ks) {
        STAGE(cur ^ 1, ks + 1);                       // 6 loads in flight
        asm volatile("s_waitcnt vmcnt(6)" ::: "memory");   // cur tile landed
        __builtin_amdgcn_s_barrier();
        __builtin_amdgcn_sched_barrier(0);
        COMPUTE(cur);
        __builtin_amdgcn_sched_barrier(0);
        __builtin_amdgcn_s_barrier();
        __builtin_amdgcn_sched_barrier(0);
        cur ^= 1;
    }
    asm volatile("s_waitcnt vmcnt(0)" ::: "memory");
    __builtin_amdgcn_s_barrier();
    __builtin_amdgcn_sched_barrier(0);
    COMPUTE(cur);

    const int cro = (l >> 4) << 2;
#pragma unroll
    for (int n = 0; n < 4; ++n) {
        const int col = wn * 64 + n * 16 + fr;
        const float bi = bias[col];
#pragma unroll
        for (int m = 0; m < 4; ++m) {
            const int rbase = row0 + wm * 64 + m * 16 + cro;
#pragma unroll
            for (int j = 0; j < 4; ++j) {
                const int r = rbase + j;
                if (r < vrows) {
                    const float v = acc[m][n][j] + bi;
                    if constexpr (RELU_OUT)
                        Ch[(size_t)r * D_FEAT + col] = (_Float16)fmaxf(v, 0.f);
                    else
                        Cf[(size_t)r * D_FEAT + col] = v;
                }
            }
        }
    }
}

// dis+chem GEMM: grid = (BX, 2); y=0 -> dis (NSEG=4), y=1 -> chem (NSEG=2)
template <bool RELU_OUT>
__global__ __launch_bounds__(512) void gemm2_k(
    const _Float16* __restrict__ A0d, const _Float16* __restrict__ A1,
    const _Float16* __restrict__ A2, const _Float16* __restrict__ A3,
    const _Float16* __restrict__ WTd, const float* __restrict__ biasd,
    float* __restrict__ Cfd, _Float16* __restrict__ Chd,
    const _Float16* __restrict__ A0c, const _Float16* __restrict__ A4,
    const _Float16* __restrict__ WTc, const float* __restrict__ biasc,
    float* __restrict__ Cfc, _Float16* __restrict__ Chc, int vrows) {
    __shared__ _Float16 Asl[2 * 128 * 64];   // 32 KB
    __shared__ _Float16 Bsl[2 * 256 * 64];   // 64 KB
    const int row0 = blockIdx.x * 128;
    if (blockIdx.y == 0)
        gemm_body<4, RELU_OUT>(Asl, Bsl, A0d, A1, A2, A3, WTd, biasd, Cfd, Chd, vrows, row0);
    else
        gemm_body<2, RELU_OUT>(Asl, Bsl, A0c, A4, nullptr, nullptr, WTc, biasc, Cfc, Chc, vrows, row0);
}

// ---------------------------------------------------------------------------
extern "C" void kernel_launch(void* const* d_in, const int* in_sizes, int n_in,
                              void* d_out, int out_size, void* d_ws, size_t ws_size,
                              hipStream_t stream) {
    const float* x_chem = (const float*)d_in[0];
    const float* x_dis  = (const float*)d_in[1];
    const float* Wl     = (const float*)d_in[2];
    const float* bl     = (const float*)d_in[3];
    const float* Wr     = (const float*)d_in[4];
    const int* ei[4] = {(const int*)d_in[5],   // cause  (chem->dis)
                        (const int*)d_in[6],   // relate (chem->dis)
                        (const int*)d_in[7],   // rev    (dis->chem)
                        (const int*)d_in[8]};  // child  (dis->dis)

    float* out_chem = (float*)d_out;
    float* out_dis  = out_chem + (size_t)N_CHEM * D_FEAT;

    // ---- workspace carve (bytes); padded feature buffers = NPAD rows ----
    constexpr size_t FB = (size_t)NPAD * D_FEAT * 2;   // 102,432,768
    char* w = (char*)d_ws;
    _Float16* h_chem  = (_Float16*)(w);
    _Float16* h_dis   = (_Float16*)(w + FB);
    _Float16* xb_chem = (_Float16*)(w + 2 * FB);
    _Float16* xb_dis  = (_Float16*)(w + 3 * FB);
    char* p = w + 4 * FB;
    int* csr    = (int*)(p);              p += 8000000;
    int* counts = (int*)(p);              p += 3200000;
    int* offs   = (int*)(p);              p += 3200000;
    int* cursor = (int*)(p);              p += 3200000;
    int* bsums  = (int*)(p);              p += 16384;
    _Float16* WT_dis  = (_Float16*)(p);   p += 1048576;
    _Float16* WT_chem = (_Float16*)(p);   p += 524288;
    float* bsum = (float*)(p);            p += 2048;
    _Float16* chunkbuf = (_Float16*)(p);  // 4 * crp * 512 bytes

    // chunk rows: 51200 keeps the 4 agg buffers (105 MB) L3-resident
    const size_t FIXED = (size_t)(p - w);
    long long avail = (long long)ws_size - (long long)FIXED;
    int crp = 51200;
    if (avail < (long long)crp * 2048) {
        long long c = avail / 2048;
        if (c > NPAD) c = NPAD;
        crp = (int)(c & ~127LL);
        if (crp < 128) crp = 128;
    }
    const int nc = (NROWS + crp - 1) / crp;

    // ---- CSR build + prep: 5 dispatches ----
    const int eall_grid = (NEALL + 255) / 256;
    const int scan_blocks = (NCNT + 255) / 256;         // 3125
    hipMemsetAsync(counts, 0, NCNT * sizeof(int), stream);
    prep_k<<<PB_CNT + 2 * PB_CVT + 2 * PB_WT, 256, 0, stream>>>(
        ei[0], ei[1], ei[2], ei[3], counts,
        x_chem, xb_chem, x_dis, xb_dis, Wl, Wr, bl, WT_dis, WT_chem, bsum);
    scan1_k<<<scan_blocks, 256, 0, stream>>>(counts, offs, cursor, bsums, NCNT);
    scan2_k<<<1, 1024, 0, stream>>>(bsums, scan_blocks);
    fill_all_k<<<eall_grid, 256, 0, stream>>>(ei[0], ei[1], ei[2], ei[3], cursor, bsums, csr);

    _Float16* slot0 = chunkbuf;                                   // cause  (dis)
    _Float16* slot1 = chunkbuf + (size_t)1 * crp * D_FEAT;        // relate (dis)
    _Float16* slot2 = chunkbuf + (size_t)2 * crp * D_FEAT;        // child  (dis)
    _Float16* slot3 = chunkbuf + (size_t)3 * crp * D_FEAT;        // rev    (chem)

    // ---- two layers, chunked: gather then gemm (r10 structure) ----
    for (int layer = 0; layer < 2; ++layer) {
        const _Float16* srcA = layer ? h_chem : xb_chem;   // chem-sourced
        const _Float16* srcB = layer ? h_dis  : xb_dis;    // dis-sourced
        const _Float16* WTd = WT_dis + (size_t)layer * 262144;
        const _Float16* WTc = WT_chem + (size_t)layer * 131072;
        const float* biasd = bsum + layer * 256;
        const float* biasc = bl + (layer * 4 + 2) * 256;

        for (int i = 0; i < nc; ++i) {
            const int base = i * crp;
            const int rows = (NROWS - base < crp) ? (NROWS - base) : crp;
            const int rows_pad = (rows + 127) & ~127;
            const size_t boff = (size_t)base * D_FEAT;
            const dim3 ggrid((rows + 15) / 16, 4);
            const dim3 mgrid(rows_pad / 128, 2);
            gather_all_k<<<ggrid, 256, 0, stream>>>(srcA, srcB, csr, offs, bsums,
                                                    counts, chunkbuf, crp, base, rows);
            if (layer == 0)
                gemm2_k<true><<<mgrid, 512, 0, stream>>>(
                    srcB + boff, slot0, slot1, slot2, WTd, biasd,
                    nullptr, h_dis + boff,
                    srcA + boff, slot3, WTc, biasc,
                    nullptr, h_chem + boff, rows);
            else
                gemm2_k<false><<<mgrid, 512, 0, stream>>>(
                    srcB + boff, slot0, slot1, slot2, WTd, biasd,
                    out_dis + boff, nullptr,
                    srcA + boff, slot3, WTc, biasc,
                    out_chem + boff, nullptr, rows);
        }
    }
}